// Round 8
// baseline (333.593 us; speedup 1.0000x reference)
//
#include <hip/hip_runtime.h>

#define HEADS 4
#define DIM_HEAD 32
#define NB 2
#define NC 256
#define HW 4096
#define HIDDEN 128
#define NBH (NB*HEADS)
#define ROWS_TOTAL (NBH*HW)   // 32768

typedef _Float16 f16;
typedef _Float16 f16x8 __attribute__((ext_vector_type(8)));
typedef _Float16 f16x4 __attribute__((ext_vector_type(4)));
typedef __fp16 fp16x2 __attribute__((ext_vector_type(2)));
typedef float f32x4 __attribute__((ext_vector_type(4)));

// workspace layout (bytes)
#define XT_OFF   0u                       // f16 [b][s][c256]     4 MB
#define QT_OFF   (4u<<20)                 // f16 [bh][s][d32]     2 MB
#define KT_OFF   (6u<<20)                 // f16 [bh][s][d32]     2 MB
#define VH_OFF   (8u<<20)                 // f16 [bh][jt128][d32][j32]  2 MB
#define HIDT_OFF (10u<<20)                // f16 [b][s][c128]     2 MB
#define WQH_OFF  (12u<<20)                // f16 [384][256]       192 KB
#define WOH_OFF  ((12u<<20) + (256u<<10)) // f16 [256][128]       64 KB
#define PART_OFF (13u<<20)                // f32 [split][33][32768]

__device__ __forceinline__ f16x8 ldg_f16x8(const f16* p) {
    union { uint4 u; f16x8 v; } t;
    t.u = *reinterpret_cast<const uint4*>(p);
    return t.v;
}
__device__ __forceinline__ f16x4 ldg_f16x4(const f16* p) {
    union { uint2 u; f16x4 v; } t;
    t.u = *reinterpret_cast<const uint2*>(p);
    return t.v;
}
__device__ __forceinline__ unsigned packh2(float a, float b) {
    union { fp16x2 h; unsigned u; } t;
    t.h = __builtin_amdgcn_cvt_pkrtz(a, b);
    return t.u;
}

// ---------------------------------------------------------------------------
// prep: fused weight-convert (wconv) + x transpose (xpose).
//   blocks [0,512):  x[b][c][s] fp32 -> XT[b][s][c] f16 via 64x64 LDS tile
//   blocks [512,640): WQH (permuted/scaled qkv weights) + WOH f16
// ---------------------------------------------------------------------------
__global__ __launch_bounds__(256) void prep(const float* __restrict__ x,
                                            const float* __restrict__ wqkv,
                                            const float* __restrict__ wout,
                                            f16* __restrict__ xt,
                                            f16* __restrict__ wqh,
                                            f16* __restrict__ woh) {
    __shared__ float T[64][65];
    const int bid = blockIdx.x;
    const float QSCALE = 0.17677669529663687f * 1.4426950408889634f;
    if (bid < 512) {
        const int s0 = (bid & 63) * 64, c0 = ((bid >> 6) & 3) * 64, b = bid >> 8;
        const int t = threadIdx.x;
        #pragma unroll
        for (int i = 0; i < 16; ++i) {
            int e = t + i * 256;
            int c = e >> 6, s = e & 63;
            T[c][s] = x[((size_t)(b * NC + c0 + c)) * HW + s0 + s];
        }
        __syncthreads();
        const int s = t >> 2, cg = (t & 3) * 16;
        unsigned ov[8];
        #pragma unroll
        for (int i = 0; i < 8; ++i)
            ov[i] = packh2(T[cg + 2 * i][s], T[cg + 2 * i + 1][s]);
        f16* dst = xt + ((size_t)(b * HW + s0 + s)) * 256 + c0 + cg;
        *reinterpret_cast<uint4*>(dst)     = make_uint4(ov[0], ov[1], ov[2], ov[3]);
        *reinterpret_cast<uint4*>(dst + 8) = make_uint4(ov[4], ov[5], ov[6], ov[7]);
    } else {
        const int tid = (bid - 512) * 256 + threadIdx.x;
        if (tid < 24576) {                       // 384*256/4
            int o_lin = tid >> 6;
            int c4 = (tid & 63) * 4;
            int which = o_lin >> 7, r = o_lin & 127;
            int head = r >> 5, d = r & 31;
            int o_g = head * 96 + d * 3 + which;
            float4 v = *reinterpret_cast<const float4*>(wqkv + o_g * 256 + c4);
            float scl = (which == 0) ? QSCALE : 1.0f;
            uint2 pv;
            pv.x = packh2(v.x * scl, v.y * scl);
            pv.y = packh2(v.z * scl, v.w * scl);
            *reinterpret_cast<uint2*>(wqh + o_lin * 256 + c4) = pv;
        } else if (tid < 24576 + 8192) {         // 256*128/4
            int t2 = tid - 24576;
            float4 v = *reinterpret_cast<const float4*>(wout + t2 * 4);
            uint2 pv;
            pv.x = packh2(v.x, v.y);
            pv.y = packh2(v.z, v.w);
            *reinterpret_cast<uint2*>(woh + t2 * 4) = pv;
        }
    }
}

// ---------------------------------------------------------------------------
// qkv_mfma: C[s][o_lin] = XT * WQH^T  (f16 MFMA, K=256)
// ---------------------------------------------------------------------------
__global__ __launch_bounds__(256) void qkv_mfma(const f16* __restrict__ xt,
                                                const f16* __restrict__ wqh,
                                                f16* __restrict__ qt,
                                                f16* __restrict__ kt,
                                                f16* __restrict__ vh) {
    const int w = threadIdx.x >> 6, lane = threadIdx.x & 63;
    const int q15 = lane & 15, quad = lane >> 4;
    const int b = blockIdx.z;
    const int sTile = blockIdx.x * 64 + (w & 1) * 32;
    const int oTile = blockIdx.y * 64 + (w >> 1) * 32;
    const f16* A = xt + ((size_t)(b * HW + sTile)) * 256;

    f32x4 acc[2][2];
    #pragma unroll
    for (int i = 0; i < 2; ++i)
        #pragma unroll
        for (int j = 0; j < 2; ++j) acc[i][j] = (f32x4){0.f, 0.f, 0.f, 0.f};

    #pragma unroll
    for (int kc = 0; kc < 256; kc += 32) {
        f16x8 a0 = ldg_f16x8(A + (size_t)q15 * 256 + kc + quad * 8);
        f16x8 a1 = ldg_f16x8(A + (size_t)(16 + q15) * 256 + kc + quad * 8);
        f16x8 b0 = ldg_f16x8(wqh + (size_t)(oTile + q15) * 256 + kc + quad * 8);
        f16x8 b1 = ldg_f16x8(wqh + (size_t)(oTile + 16 + q15) * 256 + kc + quad * 8);
        acc[0][0] = __builtin_amdgcn_mfma_f32_16x16x32_f16(a0, b0, acc[0][0], 0, 0, 0);
        acc[0][1] = __builtin_amdgcn_mfma_f32_16x16x32_f16(a0, b1, acc[0][1], 0, 0, 0);
        acc[1][0] = __builtin_amdgcn_mfma_f32_16x16x32_f16(a1, b0, acc[1][0], 0, 0, 0);
        acc[1][1] = __builtin_amdgcn_mfma_f32_16x16x32_f16(a1, b1, acc[1][1], 0, 0, 0);
    }

    #pragma unroll
    for (int si = 0; si < 2; ++si)
        #pragma unroll
        for (int oj = 0; oj < 2; ++oj) {
            int o_lin = oTile + oj * 16 + q15;
            int which = o_lin >> 7;           // wave-uniform (tiles pure)
            int r = o_lin & 127;
            int head = r >> 5, d = r & 31;
            int bh = b * HEADS + head;
            int s2 = sTile + si * 16 + quad * 4;
            if (which == 2) {
                // V tile layout: [bh][jt=s2>>5][d][jin=s2&31]
                uint2 pv;
                pv.x = packh2(acc[si][oj][0], acc[si][oj][1]);
                pv.y = packh2(acc[si][oj][2], acc[si][oj][3]);
                f16* dst = vh + (((size_t)(bh * 128 + (s2 >> 5)) * 32 + d) * 32) + (s2 & 31);
                *reinterpret_cast<uint2*>(dst) = pv;
            } else {
                f16* dst = (which == 0 ? qt : kt) + (size_t)bh * HW * 32;
                #pragma unroll
                for (int r2 = 0; r2 < 4; ++r2)
                    dst[(size_t)(s2 + r2) * 32 + d] = (f16)acc[si][oj][r2];
            }
        }
}

// ---------------------------------------------------------------------------
// attn_mfma: MFMA flash attention, no-max softmax, split-K over j.
// Register-direct P (QK C-layout == K=16 PV B-layout), V in 1KB [d32][j32]
// tiles.  2-deep K/V register prefetch: chunk i+2 loads issue before chunk i
// compute -> ~2 iterations (~500 cyc) of latency slack, 12 loads in flight.
// ---------------------------------------------------------------------------
__global__ __launch_bounds__(256) void attn_mfma(const f16* __restrict__ qt,
                                                 const f16* __restrict__ kt,
                                                 const f16* __restrict__ vh,
                                                 float* __restrict__ part, int jspan) {
    const int w    = threadIdx.x >> 6;
    const int lane = threadIdx.x & 63;
    const int q15  = lane & 15;
    const int quad = lane >> 4;
    const int bh    = blockIdx.y;
    const int split = blockIdx.z;
    const int qbase = (blockIdx.x * 4 + w) * 32;

    const f16* Qb = qt + (size_t)bh * HW * 32;
    const f16* Kp = kt + (size_t)bh * HW * 32 + (size_t)(split * jspan) * 32;
    const f16* Vp = vh + (size_t)bh * 32 * HW + (size_t)(split * jspan) * 32;

    // lane-constant offsets
    const int ko0 = q15 * 32 + quad * 8;
    const int ko1 = (16 + q15) * 32 + quad * 8;
    const int vo0 = q15 * 32 + quad * 4;
    const int vo1 = (16 + q15) * 32 + quad * 4;

    f16x8 qf0 = ldg_f16x8(Qb + (size_t)(qbase + q15) * 32 + quad * 8);
    f16x8 qf1 = ldg_f16x8(Qb + (size_t)(qbase + 16 + q15) * 32 + quad * 8);

    f32x4 acc[2][2];
    #pragma unroll
    for (int a = 0; a < 2; ++a)
        #pragma unroll
        for (int b2 = 0; b2 < 2; ++b2)
            acc[a][b2] = (f32x4){0.f, 0.f, 0.f, 0.f};
    float l0 = 0.f, l1 = 0.f;

    // 2-stage pipeline registers
    f16x8 kf0[2], kf1[2];
    f16x4 vf00[2], vf01[2], vf10[2], vf11[2];
    #pragma unroll
    for (int st = 0; st < 2; ++st) {
        kf0[st]  = ldg_f16x8(Kp + st * 1024 + ko0);
        kf1[st]  = ldg_f16x8(Kp + st * 1024 + ko1);
        vf00[st] = ldg_f16x4(Vp + st * 1024 + vo0);
        vf01[st] = ldg_f16x4(Vp + st * 1024 + vo1);
        vf10[st] = ldg_f16x4(Vp + st * 1024 + vo0 + 16);
        vf11[st] = ldg_f16x4(Vp + st * 1024 + vo1 + 16);
    }
    Kp += 2048; Vp += 2048;

    const int nch = jspan >> 5;
    for (int i = 0; i < nch; ++i) {
        const int cur = i & 1;
        // prefetch chunk i+2 (may read past split end into adjacent ws: unused)
        f16x8 nk0  = ldg_f16x8(Kp + ko0);
        f16x8 nk1  = ldg_f16x8(Kp + ko1);
        f16x4 nv00 = ldg_f16x4(Vp + vo0);
        f16x4 nv01 = ldg_f16x4(Vp + vo1);
        f16x4 nv10 = ldg_f16x4(Vp + vo0 + 16);
        f16x4 nv11 = ldg_f16x4(Vp + vo1 + 16);
        Kp += 1024; Vp += 1024;

        const f32x4 z = {0.f, 0.f, 0.f, 0.f};
        #pragma unroll
        for (int qb = 0; qb < 2; ++qb) {
            f16x8 qf = qb ? qf1 : qf0;
            f32x4 s0 = __builtin_amdgcn_mfma_f32_16x16x32_f16(kf0[cur], qf, z, 0, 0, 0);
            f32x4 s1 = __builtin_amdgcn_mfma_f32_16x16x32_f16(kf1[cur], qf, z, 0, 0, 0);
            float e0[4], e1[4];
            #pragma unroll
            for (int r = 0; r < 4; ++r) {
                e0[r] = __builtin_amdgcn_exp2f(s0[r]);
                e1[r] = __builtin_amdgcn_exp2f(s1[r]);
            }
            float ls = ((e0[0] + e0[1]) + (e0[2] + e0[3]))
                     + ((e1[0] + e1[1]) + (e1[2] + e1[3]));
            if (qb) l1 += ls; else l0 += ls;
            union { unsigned u[2]; f16x4 v; } p0, p1;
            p0.u[0] = packh2(e0[0], e0[1]);
            p0.u[1] = packh2(e0[2], e0[3]);
            p1.u[0] = packh2(e1[0], e1[1]);
            p1.u[1] = packh2(e1[2], e1[3]);
            acc[qb][0] = __builtin_amdgcn_mfma_f32_16x16x16f16(vf00[cur], p0.v, acc[qb][0], 0, 0, 0);
            acc[qb][1] = __builtin_amdgcn_mfma_f32_16x16x16f16(vf01[cur], p0.v, acc[qb][1], 0, 0, 0);
            acc[qb][0] = __builtin_amdgcn_mfma_f32_16x16x16f16(vf10[cur], p1.v, acc[qb][0], 0, 0, 0);
            acc[qb][1] = __builtin_amdgcn_mfma_f32_16x16x16f16(vf11[cur], p1.v, acc[qb][1], 0, 0, 0);
        }
        kf0[cur] = nk0; kf1[cur] = nk1;
        vf00[cur] = nv00; vf01[cur] = nv01; vf10[cur] = nv10; vf11[cur] = nv11;
    }

    float* P = part + (size_t)split * 33 * ROWS_TOTAL;
    #pragma unroll
    for (int qb = 0; qb < 2; ++qb) {
        float lv = qb ? l1 : l0;
        lv += __shfl_xor(lv, 16, 64);
        lv += __shfl_xor(lv, 32, 64);
        const int grow = bh * HW + qbase + qb * 16 + q15;
        if (quad == 0) P[grow] = lv;
        #pragma unroll
        for (int t = 0; t < 2; ++t)
            #pragma unroll
            for (int r = 0; r < 4; ++r) {
                int d = t * 16 + quad * 4 + r;
                P[(size_t)(1 + d) * ROWS_TOTAL + grow] = acc[qb][t][r];
            }
    }
}

// ---------------------------------------------------------------------------
// attn_merge: sum S additive splits, normalize, write HIDT f16 [b][s][c128].
// ---------------------------------------------------------------------------
__global__ __launch_bounds__(256) void attn_merge(const float* __restrict__ part,
                                                  f16* __restrict__ hidt, int S) {
    const int dq   = blockIdx.x & 7;                       // d-eighth: 4 d's
    const int grow = (blockIdx.x >> 3) * 256 + threadIdx.x; // 0..32767
    float l = 0.f;
    for (int sp = 0; sp < S; ++sp)
        l += part[(size_t)sp * 33 * ROWS_TOTAL + grow];
    const float inv = 1.0f / l;

    unsigned ov[2];
    #pragma unroll
    for (int d2 = 0; d2 < 2; ++d2) {
        int d = dq * 4 + d2 * 2;
        float o0 = 0.f, o1 = 0.f;
        for (int sp = 0; sp < S; ++sp) {
            const float* P = part + (size_t)sp * 33 * ROWS_TOTAL + grow;
            o0 += P[(size_t)(1 + d) * ROWS_TOTAL];
            o1 += P[(size_t)(2 + d) * ROWS_TOTAL];
        }
        ov[d2] = packh2(o0 * inv, o1 * inv);
    }
    const int bh = grow >> 12, s = grow & 4095;
    const int b = bh >> 2, h = bh & 3;
    f16* dst = hidt + ((size_t)(b * HW + s)) * 128 + h * 32 + dq * 4;
    *reinterpret_cast<uint2*>(dst) = make_uint2(ov[0], ov[1]);
}

// ---------------------------------------------------------------------------
// outp_mfma: out[b][o][s] = HIDT * WOH^T + bias  (f16 MFMA, K=128, fp32 out)
// ---------------------------------------------------------------------------
__global__ __launch_bounds__(256) void outp_mfma(const f16* __restrict__ hidt,
                                                 const f16* __restrict__ woh,
                                                 const float* __restrict__ bout,
                                                 float* __restrict__ out) {
    const int w = threadIdx.x >> 6, lane = threadIdx.x & 63;
    const int q15 = lane & 15, quad = lane >> 4;
    const int b = blockIdx.z;
    const int sTile = blockIdx.x * 64 + (w & 1) * 32;
    const int oTile = blockIdx.y * 64 + (w >> 1) * 32;
    const f16* A = hidt + ((size_t)(b * HW + sTile)) * 128;

    f32x4 acc[2][2];
    #pragma unroll
    for (int i = 0; i < 2; ++i)
        #pragma unroll
        for (int j = 0; j < 2; ++j) acc[i][j] = (f32x4){0.f, 0.f, 0.f, 0.f};

    #pragma unroll
    for (int kc = 0; kc < 128; kc += 32) {
        f16x8 a0 = ldg_f16x8(A + (size_t)q15 * 128 + kc + quad * 8);
        f16x8 a1 = ldg_f16x8(A + (size_t)(16 + q15) * 128 + kc + quad * 8);
        f16x8 b0 = ldg_f16x8(woh + (size_t)(oTile + q15) * 128 + kc + quad * 8);
        f16x8 b1 = ldg_f16x8(woh + (size_t)(oTile + 16 + q15) * 128 + kc + quad * 8);
        acc[0][0] = __builtin_amdgcn_mfma_f32_16x16x32_f16(a0, b0, acc[0][0], 0, 0, 0);
        acc[0][1] = __builtin_amdgcn_mfma_f32_16x16x32_f16(a0, b1, acc[0][1], 0, 0, 0);
        acc[1][0] = __builtin_amdgcn_mfma_f32_16x16x32_f16(a1, b0, acc[1][0], 0, 0, 0);
        acc[1][1] = __builtin_amdgcn_mfma_f32_16x16x32_f16(a1, b1, acc[1][1], 0, 0, 0);
    }

    #pragma unroll
    for (int oj = 0; oj < 2; ++oj) {
        const int o = oTile + oj * 16 + q15;
        const float bias = bout[o];
        #pragma unroll
        for (int si = 0; si < 2; ++si) {
            const int s2 = sTile + si * 16 + quad * 4;
            float4 v = make_float4(acc[si][oj][0] + bias, acc[si][oj][1] + bias,
                                   acc[si][oj][2] + bias, acc[si][oj][3] + bias);
            *reinterpret_cast<float4*>(out + ((size_t)(b * NC + o)) * HW + s2) = v;
        }
    }
}

// ---------------------------------------------------------------------------
extern "C" void kernel_launch(void* const* d_in, const int* in_sizes, int n_in,
                              void* d_out, int out_size, void* d_ws, size_t ws_size,
                              hipStream_t stream) {
    const float* x    = (const float*)d_in[0];
    const float* wqkv = (const float*)d_in[1];
    const float* wout = (const float*)d_in[2];
    const float* bout = (const float*)d_in[3];
    float* out = (float*)d_out;
    char* wsb  = (char*)d_ws;

    f16*   XT   = (f16*)(wsb + XT_OFF);
    f16*   QT   = (f16*)(wsb + QT_OFF);
    f16*   KT   = (f16*)(wsb + KT_OFF);
    f16*   VH   = (f16*)(wsb + VH_OFF);
    f16*   HIDT = (f16*)(wsb + HIDT_OFF);
    f16*   WQH  = (f16*)(wsb + WQH_OFF);
    f16*   WOH  = (f16*)(wsb + WOH_OFF);
    float* PART = (float*)(wsb + PART_OFF);

    // deterministic split-count from ws_size (graph-capture safe)
    int S = 8;
    while (S > 1 && (size_t)PART_OFF + (size_t)S * 33 * ROWS_TOTAL * 4 > ws_size)
        S >>= 1;

    prep     <<<dim3(640), 256, 0, stream>>>(x, wqkv, wout, XT, WQH, WOH);
    qkv_mfma <<<dim3(64, 6, NB), 256, 0, stream>>>(XT, WQH, QT, KT, VH);
    attn_mfma<<<dim3(32, NBH, S), 256, 0, stream>>>(QT, KT, VH, PART, HW / S);
    attn_merge<<<dim3(1024), 256, 0, stream>>>(PART, HIDT, S);
    outp_mfma<<<dim3(64, 4, NB), 256, 0, stream>>>(HIDT, WOH, bout, out);
}

// Round 9
// 147.707 us; speedup vs baseline: 2.2585x; 2.2585x over previous
//
#include <hip/hip_runtime.h>

#define HEADS 4
#define DIM_HEAD 32
#define NB 2
#define NC 256
#define HW 4096
#define HIDDEN 128
#define NBH (NB*HEADS)
#define ROWS_TOTAL (NBH*HW)   // 32768

typedef _Float16 f16;
typedef _Float16 f16x8 __attribute__((ext_vector_type(8)));
typedef _Float16 f16x4 __attribute__((ext_vector_type(4)));
typedef __fp16 fp16x2 __attribute__((ext_vector_type(2)));
typedef float f32x4 __attribute__((ext_vector_type(4)));

// workspace layout (bytes)
#define XT_OFF   0u                       // f16 [b][s][c256]     4 MB
#define QT_OFF   (4u<<20)                 // f16 [bh][s][d32]     2 MB
#define KT_OFF   (6u<<20)                 // f16 [bh][s][d32]     2 MB
#define VH_OFF   (8u<<20)                 // f16 [bh][jt128][d32][j32]  2 MB
#define HIDT_OFF (10u<<20)                // f16 [b][s][c128]     2 MB
#define WQH_OFF  (12u<<20)                // f16 [384][256]       192 KB
#define WOH_OFF  ((12u<<20) + (256u<<10)) // f16 [256][128]       64 KB
#define PART_OFF (13u<<20)                // f32 [split][33][32768]

__device__ __forceinline__ f16x8 ldg_f16x8(const f16* p) {
    union { uint4 u; f16x8 v; } t;
    t.u = *reinterpret_cast<const uint4*>(p);
    return t.v;
}
__device__ __forceinline__ f16x4 ldg_f16x4(const f16* p) {
    union { uint2 u; f16x4 v; } t;
    t.u = *reinterpret_cast<const uint2*>(p);
    return t.v;
}
__device__ __forceinline__ unsigned packh2(float a, float b) {
    union { fp16x2 h; unsigned u; } t;
    t.h = __builtin_amdgcn_cvt_pkrtz(a, b);
    return t.u;
}

// ---------------------------------------------------------------------------
// prep: fused weight-convert + x transpose.
// ---------------------------------------------------------------------------
__global__ __launch_bounds__(256) void prep(const float* __restrict__ x,
                                            const float* __restrict__ wqkv,
                                            const float* __restrict__ wout,
                                            f16* __restrict__ xt,
                                            f16* __restrict__ wqh,
                                            f16* __restrict__ woh) {
    __shared__ float T[64][65];
    const int bid = blockIdx.x;
    const float QSCALE = 0.17677669529663687f * 1.4426950408889634f;
    if (bid < 512) {
        const int s0 = (bid & 63) * 64, c0 = ((bid >> 6) & 3) * 64, b = bid >> 8;
        const int t = threadIdx.x;
        #pragma unroll
        for (int i = 0; i < 16; ++i) {
            int e = t + i * 256;
            int c = e >> 6, s = e & 63;
            T[c][s] = x[((size_t)(b * NC + c0 + c)) * HW + s0 + s];
        }
        __syncthreads();
        const int s = t >> 2, cg = (t & 3) * 16;
        unsigned ov[8];
        #pragma unroll
        for (int i = 0; i < 8; ++i)
            ov[i] = packh2(T[cg + 2 * i][s], T[cg + 2 * i + 1][s]);
        f16* dst = xt + ((size_t)(b * HW + s0 + s)) * 256 + c0 + cg;
        *reinterpret_cast<uint4*>(dst)     = make_uint4(ov[0], ov[1], ov[2], ov[3]);
        *reinterpret_cast<uint4*>(dst + 8) = make_uint4(ov[4], ov[5], ov[6], ov[7]);
    } else {
        const int tid = (bid - 512) * 256 + threadIdx.x;
        if (tid < 24576) {                       // 384*256/4
            int o_lin = tid >> 6;
            int c4 = (tid & 63) * 4;
            int which = o_lin >> 7, r = o_lin & 127;
            int head = r >> 5, d = r & 31;
            int o_g = head * 96 + d * 3 + which;
            float4 v = *reinterpret_cast<const float4*>(wqkv + o_g * 256 + c4);
            float scl = (which == 0) ? QSCALE : 1.0f;
            uint2 pv;
            pv.x = packh2(v.x * scl, v.y * scl);
            pv.y = packh2(v.z * scl, v.w * scl);
            *reinterpret_cast<uint2*>(wqh + o_lin * 256 + c4) = pv;
        } else if (tid < 24576 + 8192) {         // 256*128/4
            int t2 = tid - 24576;
            float4 v = *reinterpret_cast<const float4*>(wout + t2 * 4);
            uint2 pv;
            pv.x = packh2(v.x, v.y);
            pv.y = packh2(v.z, v.w);
            *reinterpret_cast<uint2*>(woh + t2 * 4) = pv;
        }
    }
}

// ---------------------------------------------------------------------------
// qkv_mfma: C[s][o_lin] = XT * WQH^T  (f16 MFMA, K=256)
// ---------------------------------------------------------------------------
__global__ __launch_bounds__(256) void qkv_mfma(const f16* __restrict__ xt,
                                                const f16* __restrict__ wqh,
                                                f16* __restrict__ qt,
                                                f16* __restrict__ kt,
                                                f16* __restrict__ vh) {
    const int w = threadIdx.x >> 6, lane = threadIdx.x & 63;
    const int q15 = lane & 15, quad = lane >> 4;
    const int b = blockIdx.z;
    const int sTile = blockIdx.x * 64 + (w & 1) * 32;
    const int oTile = blockIdx.y * 64 + (w >> 1) * 32;
    const f16* A = xt + ((size_t)(b * HW + sTile)) * 256;

    f32x4 acc[2][2];
    #pragma unroll
    for (int i = 0; i < 2; ++i)
        #pragma unroll
        for (int j = 0; j < 2; ++j) acc[i][j] = (f32x4){0.f, 0.f, 0.f, 0.f};

    #pragma unroll
    for (int kc = 0; kc < 256; kc += 32) {
        f16x8 a0 = ldg_f16x8(A + (size_t)q15 * 256 + kc + quad * 8);
        f16x8 a1 = ldg_f16x8(A + (size_t)(16 + q15) * 256 + kc + quad * 8);
        f16x8 b0 = ldg_f16x8(wqh + (size_t)(oTile + q15) * 256 + kc + quad * 8);
        f16x8 b1 = ldg_f16x8(wqh + (size_t)(oTile + 16 + q15) * 256 + kc + quad * 8);
        acc[0][0] = __builtin_amdgcn_mfma_f32_16x16x32_f16(a0, b0, acc[0][0], 0, 0, 0);
        acc[0][1] = __builtin_amdgcn_mfma_f32_16x16x32_f16(a0, b1, acc[0][1], 0, 0, 0);
        acc[1][0] = __builtin_amdgcn_mfma_f32_16x16x32_f16(a1, b0, acc[1][0], 0, 0, 0);
        acc[1][1] = __builtin_amdgcn_mfma_f32_16x16x32_f16(a1, b1, acc[1][1], 0, 0, 0);
    }

    #pragma unroll
    for (int si = 0; si < 2; ++si)
        #pragma unroll
        for (int oj = 0; oj < 2; ++oj) {
            int o_lin = oTile + oj * 16 + q15;
            int which = o_lin >> 7;           // wave-uniform (tiles pure)
            int r = o_lin & 127;
            int head = r >> 5, d = r & 31;
            int bh = b * HEADS + head;
            int s2 = sTile + si * 16 + quad * 4;
            if (which == 2) {
                // V tile layout: [bh][jt=s2>>5][d][jin=s2&31]
                uint2 pv;
                pv.x = packh2(acc[si][oj][0], acc[si][oj][1]);
                pv.y = packh2(acc[si][oj][2], acc[si][oj][3]);
                f16* dst = vh + (((size_t)(bh * 128 + (s2 >> 5)) * 32 + d) * 32) + (s2 & 31);
                *reinterpret_cast<uint2*>(dst) = pv;
            } else {
                f16* dst = (which == 0 ? qt : kt) + (size_t)bh * HW * 32;
                #pragma unroll
                for (int r2 = 0; r2 < 4; ++r2)
                    dst[(size_t)(s2 + r2) * 32 + d] = (f16)acc[si][oj][r2];
            }
        }
}

// ---------------------------------------------------------------------------
// attn_mfma: MFMA flash attention, no-max softmax, split-K over j.
// Register-direct P; V in 1KB [d32][j32] tiles.  2-deep prefetch pipeline with
// EXPLICIT stage registers and manual x2 unroll (no dynamic register indexing
// -- round 8's arr[i&1] form compiled to select-tree hell: 87% VALUBusy).
// ---------------------------------------------------------------------------
#define ATTN_CHUNK(KF0, KF1, V00, V01, V10, V11)                                    \
    {                                                                               \
        const f32x4 z = {0.f, 0.f, 0.f, 0.f};                                       \
        _Pragma("unroll")                                                           \
        for (int qb = 0; qb < 2; ++qb) {                                            \
            f16x8 qf = qb ? qf1 : qf0;                                              \
            f32x4 s0 = __builtin_amdgcn_mfma_f32_16x16x32_f16(KF0, qf, z, 0, 0, 0); \
            f32x4 s1 = __builtin_amdgcn_mfma_f32_16x16x32_f16(KF1, qf, z, 0, 0, 0); \
            float e0[4], e1[4];                                                     \
            _Pragma("unroll")                                                       \
            for (int r = 0; r < 4; ++r) {                                           \
                e0[r] = __builtin_amdgcn_exp2f(s0[r]);                              \
                e1[r] = __builtin_amdgcn_exp2f(s1[r]);                              \
            }                                                                       \
            float ls = ((e0[0] + e0[1]) + (e0[2] + e0[3]))                          \
                     + ((e1[0] + e1[1]) + (e1[2] + e1[3]));                         \
            if (qb) l1 += ls; else l0 += ls;                                        \
            union { unsigned u[2]; f16x4 v; } p0, p1;                               \
            p0.u[0] = packh2(e0[0], e0[1]);                                         \
            p0.u[1] = packh2(e0[2], e0[3]);                                         \
            p1.u[0] = packh2(e1[0], e1[1]);                                         \
            p1.u[1] = packh2(e1[2], e1[3]);                                         \
            acc[qb][0] = __builtin_amdgcn_mfma_f32_16x16x16f16(V00, p0.v, acc[qb][0], 0, 0, 0); \
            acc[qb][1] = __builtin_amdgcn_mfma_f32_16x16x16f16(V01, p0.v, acc[qb][1], 0, 0, 0); \
            acc[qb][0] = __builtin_amdgcn_mfma_f32_16x16x16f16(V10, p1.v, acc[qb][0], 0, 0, 0); \
            acc[qb][1] = __builtin_amdgcn_mfma_f32_16x16x16f16(V11, p1.v, acc[qb][1], 0, 0, 0); \
        }                                                                           \
    }

__global__ __launch_bounds__(256) void attn_mfma(const f16* __restrict__ qt,
                                                 const f16* __restrict__ kt,
                                                 const f16* __restrict__ vh,
                                                 float* __restrict__ part, int jspan) {
    const int w    = threadIdx.x >> 6;
    const int lane = threadIdx.x & 63;
    const int q15  = lane & 15;
    const int quad = lane >> 4;
    const int bh    = blockIdx.y;
    const int split = blockIdx.z;
    const int qbase = (blockIdx.x * 4 + w) * 32;

    const f16* Qb = qt + (size_t)bh * HW * 32;
    const f16* Kp = kt + (size_t)bh * HW * 32 + (size_t)(split * jspan) * 32;
    const f16* Vp = vh + (size_t)bh * 32 * HW + (size_t)(split * jspan) * 32;

    // lane-constant offsets
    const int ko0 = q15 * 32 + quad * 8;
    const int ko1 = (16 + q15) * 32 + quad * 8;
    const int vo0 = q15 * 32 + quad * 4;
    const int vo1 = (16 + q15) * 32 + quad * 4;

    f16x8 qf0 = ldg_f16x8(Qb + (size_t)(qbase + q15) * 32 + quad * 8);
    f16x8 qf1 = ldg_f16x8(Qb + (size_t)(qbase + 16 + q15) * 32 + quad * 8);

    f32x4 acc[2][2];
    #pragma unroll
    for (int a = 0; a < 2; ++a)
        #pragma unroll
        for (int b2 = 0; b2 < 2; ++b2)
            acc[a][b2] = (f32x4){0.f, 0.f, 0.f, 0.f};
    float l0 = 0.f, l1 = 0.f;

    // stage A = chunk 0, stage B = chunk 1 (explicit registers)
    f16x8 ka0  = ldg_f16x8(Kp + ko0);
    f16x8 ka1  = ldg_f16x8(Kp + ko1);
    f16x4 va00 = ldg_f16x4(Vp + vo0);
    f16x4 va01 = ldg_f16x4(Vp + vo1);
    f16x4 va10 = ldg_f16x4(Vp + vo0 + 16);
    f16x4 va11 = ldg_f16x4(Vp + vo1 + 16);
    f16x8 kb0  = ldg_f16x8(Kp + 1024 + ko0);
    f16x8 kb1  = ldg_f16x8(Kp + 1024 + ko1);
    f16x4 vb00 = ldg_f16x4(Vp + 1024 + vo0);
    f16x4 vb01 = ldg_f16x4(Vp + 1024 + vo1);
    f16x4 vb10 = ldg_f16x4(Vp + 1024 + vo0 + 16);
    f16x4 vb11 = ldg_f16x4(Vp + 1024 + vo1 + 16);
    Kp += 2048; Vp += 2048;

    const int nch = jspan >> 5;   // multiple of 2 for S in {1,2,4,8}
    for (int i = 0; i < nch; i += 2) {
        // prefetch chunk i+2 (may overrun split end into adjacent ws: unused)
        f16x8 nk0  = ldg_f16x8(Kp + ko0);
        f16x8 nk1  = ldg_f16x8(Kp + ko1);
        f16x4 nv00 = ldg_f16x4(Vp + vo0);
        f16x4 nv01 = ldg_f16x4(Vp + vo1);
        f16x4 nv10 = ldg_f16x4(Vp + vo0 + 16);
        f16x4 nv11 = ldg_f16x4(Vp + vo1 + 16);
        ATTN_CHUNK(ka0, ka1, va00, va01, va10, va11);   // compute chunk i
        ka0 = nk0; ka1 = nk1;
        va00 = nv00; va01 = nv01; va10 = nv10; va11 = nv11;

        // prefetch chunk i+3
        f16x8 mk0  = ldg_f16x8(Kp + 1024 + ko0);
        f16x8 mk1  = ldg_f16x8(Kp + 1024 + ko1);
        f16x4 mv00 = ldg_f16x4(Vp + 1024 + vo0);
        f16x4 mv01 = ldg_f16x4(Vp + 1024 + vo1);
        f16x4 mv10 = ldg_f16x4(Vp + 1024 + vo0 + 16);
        f16x4 mv11 = ldg_f16x4(Vp + 1024 + vo1 + 16);
        ATTN_CHUNK(kb0, kb1, vb00, vb01, vb10, vb11);   // compute chunk i+1
        kb0 = mk0; kb1 = mk1;
        vb00 = mv00; vb01 = mv01; vb10 = mv10; vb11 = mv11;

        Kp += 2048; Vp += 2048;
    }

    float* P = part + (size_t)split * 33 * ROWS_TOTAL;
    #pragma unroll
    for (int qb = 0; qb < 2; ++qb) {
        float lv = qb ? l1 : l0;
        lv += __shfl_xor(lv, 16, 64);
        lv += __shfl_xor(lv, 32, 64);
        const int grow = bh * HW + qbase + qb * 16 + q15;
        if (quad == 0) P[grow] = lv;
        #pragma unroll
        for (int t = 0; t < 2; ++t)
            #pragma unroll
            for (int r = 0; r < 4; ++r) {
                int d = t * 16 + quad * 4 + r;
                P[(size_t)(1 + d) * ROWS_TOTAL + grow] = acc[qb][t][r];
            }
    }
}

// ---------------------------------------------------------------------------
// attn_merge: sum S additive splits, normalize, write HIDT f16 [b][s][c128].
// ---------------------------------------------------------------------------
__global__ __launch_bounds__(256) void attn_merge(const float* __restrict__ part,
                                                  f16* __restrict__ hidt, int S) {
    const int dq   = blockIdx.x & 7;                       // d-eighth: 4 d's
    const int grow = (blockIdx.x >> 3) * 256 + threadIdx.x; // 0..32767
    float l = 0.f;
    for (int sp = 0; sp < S; ++sp)
        l += part[(size_t)sp * 33 * ROWS_TOTAL + grow];
    const float inv = 1.0f / l;

    unsigned ov[2];
    #pragma unroll
    for (int d2 = 0; d2 < 2; ++d2) {
        int d = dq * 4 + d2 * 2;
        float o0 = 0.f, o1 = 0.f;
        for (int sp = 0; sp < S; ++sp) {
            const float* P = part + (size_t)sp * 33 * ROWS_TOTAL + grow;
            o0 += P[(size_t)(1 + d) * ROWS_TOTAL];
            o1 += P[(size_t)(2 + d) * ROWS_TOTAL];
        }
        ov[d2] = packh2(o0 * inv, o1 * inv);
    }
    const int bh = grow >> 12, s = grow & 4095;
    const int b = bh >> 2, h = bh & 3;
    f16* dst = hidt + ((size_t)(b * HW + s)) * 128 + h * 32 + dq * 4;
    *reinterpret_cast<uint2*>(dst) = make_uint2(ov[0], ov[1]);
}

// ---------------------------------------------------------------------------
// outp_mfma: out[b][o][s] = HIDT * WOH^T + bias  (f16 MFMA, K=128, fp32 out)
// ---------------------------------------------------------------------------
__global__ __launch_bounds__(256) void outp_mfma(const f16* __restrict__ hidt,
                                                 const f16* __restrict__ woh,
                                                 const float* __restrict__ bout,
                                                 float* __restrict__ out) {
    const int w = threadIdx.x >> 6, lane = threadIdx.x & 63;
    const int q15 = lane & 15, quad = lane >> 4;
    const int b = blockIdx.z;
    const int sTile = blockIdx.x * 64 + (w & 1) * 32;
    const int oTile = blockIdx.y * 64 + (w >> 1) * 32;
    const f16* A = hidt + ((size_t)(b * HW + sTile)) * 128;

    f32x4 acc[2][2];
    #pragma unroll
    for (int i = 0; i < 2; ++i)
        #pragma unroll
        for (int j = 0; j < 2; ++j) acc[i][j] = (f32x4){0.f, 0.f, 0.f, 0.f};

    #pragma unroll
    for (int kc = 0; kc < 128; kc += 32) {
        f16x8 a0 = ldg_f16x8(A + (size_t)q15 * 128 + kc + quad * 8);
        f16x8 a1 = ldg_f16x8(A + (size_t)(16 + q15) * 128 + kc + quad * 8);
        f16x8 b0 = ldg_f16x8(woh + (size_t)(oTile + q15) * 128 + kc + quad * 8);
        f16x8 b1 = ldg_f16x8(woh + (size_t)(oTile + 16 + q15) * 128 + kc + quad * 8);
        acc[0][0] = __builtin_amdgcn_mfma_f32_16x16x32_f16(a0, b0, acc[0][0], 0, 0, 0);
        acc[0][1] = __builtin_amdgcn_mfma_f32_16x16x32_f16(a0, b1, acc[0][1], 0, 0, 0);
        acc[1][0] = __builtin_amdgcn_mfma_f32_16x16x32_f16(a1, b0, acc[1][0], 0, 0, 0);
        acc[1][1] = __builtin_amdgcn_mfma_f32_16x16x32_f16(a1, b1, acc[1][1], 0, 0, 0);
    }

    #pragma unroll
    for (int oj = 0; oj < 2; ++oj) {
        const int o = oTile + oj * 16 + q15;
        const float bias = bout[o];
        #pragma unroll
        for (int si = 0; si < 2; ++si) {
            const int s2 = sTile + si * 16 + quad * 4;
            float4 v = make_float4(acc[si][oj][0] + bias, acc[si][oj][1] + bias,
                                   acc[si][oj][2] + bias, acc[si][oj][3] + bias);
            *reinterpret_cast<float4*>(out + ((size_t)(b * NC + o)) * HW + s2) = v;
        }
    }
}

// ---------------------------------------------------------------------------
extern "C" void kernel_launch(void* const* d_in, const int* in_sizes, int n_in,
                              void* d_out, int out_size, void* d_ws, size_t ws_size,
                              hipStream_t stream) {
    const float* x    = (const float*)d_in[0];
    const float* wqkv = (const float*)d_in[1];
    const float* wout = (const float*)d_in[2];
    const float* bout = (const float*)d_in[3];
    float* out = (float*)d_out;
    char* wsb  = (char*)d_ws;

    f16*   XT   = (f16*)(wsb + XT_OFF);
    f16*   QT   = (f16*)(wsb + QT_OFF);
    f16*   KT   = (f16*)(wsb + KT_OFF);
    f16*   VH   = (f16*)(wsb + VH_OFF);
    f16*   HIDT = (f16*)(wsb + HIDT_OFF);
    f16*   WQH  = (f16*)(wsb + WQH_OFF);
    f16*   WOH  = (f16*)(wsb + WOH_OFF);
    float* PART = (float*)(wsb + PART_OFF);

    // deterministic split-count from ws_size (graph-capture safe)
    int S = 8;
    while (S > 1 && (size_t)PART_OFF + (size_t)S * 33 * ROWS_TOTAL * 4 > ws_size)
        S >>= 1;

    prep     <<<dim3(640), 256, 0, stream>>>(x, wqkv, wout, XT, WQH, WOH);
    qkv_mfma <<<dim3(64, 6, NB), 256, 0, stream>>>(XT, WQH, QT, KT, VH);
    attn_mfma<<<dim3(32, NBH, S), 256, 0, stream>>>(QT, KT, VH, PART, HW / S);
    attn_merge<<<dim3(1024), 256, 0, stream>>>(PART, HIDT, S);
    outp_mfma<<<dim3(64, 4, NB), 256, 0, stream>>>(HIDT, WOH, bout, out);
}